// Round 1
// baseline (347.227 us; speedup 1.0000x reference)
//
#include <hip/hip_runtime.h>
#include <hip/hip_fp16.h>

#define B_ 2
#define L_ 2048
#define D_ 1024
#define H_ 16

typedef __attribute__((ext_vector_type(8))) _Float16 f16x8;
typedef __attribute__((ext_vector_type(4))) float f32x4;

__device__ __forceinline__ void gload_lds16(const void* g, void* l) {
  __builtin_amdgcn_global_load_lds(
      (const __attribute__((address_space(1))) unsigned int*)g,
      (__attribute__((address_space(3))) unsigned int*)l, 16, 0, 0);
}

// ---------------- converts ----------------
__global__ __launch_bounds__(256) void cvt_f16(const float* __restrict__ s,
                                               __half* __restrict__ d, int n4) {
  int i = blockIdx.x * 256 + threadIdx.x;
  if (i >= n4) return;
  float4 v = ((const float4*)s)[i];
  __half2* o = (__half2*)(d + (size_t)i * 4);
  o[0] = __floats2half2_rn(v.x, v.y);
  o[1] = __floats2half2_rn(v.z, v.w);
}

__global__ __launch_bounds__(256) void cvt_mask(const int* __restrict__ s,
                                                unsigned char* __restrict__ d, int n4) {
  int i = blockIdx.x * 256 + threadIdx.x;
  if (i >= n4) return;
  int4 v = ((const int4*)s)[i];
  uchar4 o;
  o.x = v.x != 0; o.y = v.y != 0; o.z = v.z != 0; o.w = v.w != 0;
  ((uchar4*)d)[i] = o;
}

// T5 bucket -> bias table [H][4095], index = rel + 2047
__global__ __launch_bounds__(256) void bias_table(const float* __restrict__ rel_emb,
                                                  float* __restrict__ tab) {
  int i = blockIdx.x * 256 + threadIdx.x;
  if (i >= H_ * 4095) return;
  int h = i / 4095, idx = i - h * 4095;
  int rel = idx - 2047;
  int n = rel < 0 ? -rel : rel;
  int bkt;
  if (n < 8) {
    bkt = n;
  } else {
    float t = logf((float)n / 8.0f) / 2.772588722239781f * 8.0f;
    int v = 8 + (int)t;
    bkt = v < 15 ? v : 15;
  }
  if (rel > 0) bkt += 16;
  tab[i] = rel_emb[bkt * H_ + h];
}

// ---------------- GEMM core: C[128x128] = A[M,1024] * W[N,1024]^T ----------------
__device__ __forceinline__ void gemm_tile(const __half* __restrict__ A,
                                          const __half* __restrict__ Bw,
                                          int m0, int n0,
                                          __half* sA, __half* sB,
                                          f32x4 (&acc)[4][4],
                                          int lane, int wm, int wn, int t) {
  for (int k0 = 0; k0 < 1024; k0 += 64) {
    __syncthreads();
#pragma unroll
    for (int it = 0; it < 4; ++it) {
      int c = t + it * 256;
      int row = c >> 3, seg = c & 7;
      gload_lds16(A + ((size_t)(m0 + row) << 10) + k0 + seg * 8, sA + c * 8);
      gload_lds16(Bw + ((size_t)(n0 + row) << 10) + k0 + seg * 8, sB + c * 8);
    }
    __syncthreads();
#pragma unroll
    for (int kk = 0; kk < 2; ++kk) {
      const int off = kk * 32 + (lane >> 4) * 8;
      const int rr = lane & 15;
      f16x8 af[4], bf[4];
#pragma unroll
      for (int i = 0; i < 4; ++i) af[i] = *(const f16x8*)&sA[(wm * 64 + i * 16 + rr) * 64 + off];
#pragma unroll
      for (int i = 0; i < 4; ++i) bf[i] = *(const f16x8*)&sB[(wn * 64 + i * 16 + rr) * 64 + off];
#pragma unroll
      for (int mi = 0; mi < 4; ++mi)
#pragma unroll
        for (int ni = 0; ni < 4; ++ni)
          acc[mi][ni] = __builtin_amdgcn_mfma_f32_16x16x32_f16(af[mi], bf[ni], acc[mi][ni], 0, 0, 0);
    }
  }
}

// fused QKV projection: grid (32, 24); widx = which weight
__global__ __launch_bounds__(256) void gemm_qkv(
    const __half* __restrict__ xh,
    const __half* __restrict__ Wq, const __half* __restrict__ Wk, const __half* __restrict__ Wv,
    const float* __restrict__ bq, const float* __restrict__ bk, const float* __restrict__ bvv,
    __half* __restrict__ Qh, __half* __restrict__ Kh, __half* __restrict__ Vt) {
  __shared__ __align__(16) __half sA[128 * 64];
  __shared__ __align__(16) __half sB[128 * 64];
  const int m0 = blockIdx.x * 128;
  const int ng = blockIdx.y * 128;
  const int widx = ng >> 10;
  const int n0 = ng & 1023;
  const __half* Bw = widx == 0 ? Wq : (widx == 1 ? Wk : Wv);
  const float* bias = widx == 0 ? bq : (widx == 1 ? bk : bvv);
  const int t = threadIdx.x, lane = t & 63, w = t >> 6;
  const int wm = w >> 1, wn = w & 1;
  f32x4 acc[4][4] = {};
  gemm_tile(xh, Bw, m0, n0, sA, sB, acc, lane, wm, wn, t);
  const int rg = (lane >> 4) * 4, cg = lane & 15;
#pragma unroll
  for (int mi = 0; mi < 4; ++mi)
#pragma unroll
    for (int ni = 0; ni < 4; ++ni) {
      int m = m0 + wm * 64 + mi * 16 + rg;
      int n = n0 + wn * 64 + ni * 16 + cg;
      float bvx = bias[n];
      int b = m >> 11, l = m & 2047, hh = n >> 6, dd = n & 63;
      f32x4 a = acc[mi][ni];
      if (widx == 2) {
        // V transposed: Vt[(bh*64+dd)][l..l+3]  (4 consecutive l -> one 8B store)
        size_t base = ((size_t)((b * 16 + hh) * 64 + dd)) * 2048 + l;
        __half2 p0 = __floats2half2_rn(a.x + bvx, a.y + bvx);
        __half2 p1 = __floats2half2_rn(a.z + bvx, a.w + bvx);
        *(__half2*)(Vt + base) = p0;
        *(__half2*)(Vt + base + 2) = p1;
      } else {
        __half* dst = widx == 0 ? Qh : Kh;
        float scf = widx == 0 ? 0.125f : 1.0f;  // fold 1/sqrt(dk) into Q
        size_t base = (((size_t)(b * 16 + hh)) * 2048 + l) * 64 + dd;
#pragma unroll
        for (int r = 0; r < 4; ++r)
          dst[base + (size_t)r * 64] = __float2half((a[r] + bvx) * scf);
      }
    }
}

// output projection: out = AO * Wo^T + bo, fp32 result
__global__ __launch_bounds__(256) void gemm_out(
    const __half* __restrict__ AO, const __half* __restrict__ Wo,
    const float* __restrict__ bo, float* __restrict__ out) {
  __shared__ __align__(16) __half sA[128 * 64];
  __shared__ __align__(16) __half sB[128 * 64];
  const int m0 = blockIdx.x * 128;
  const int n0 = blockIdx.y * 128;
  const int t = threadIdx.x, lane = t & 63, w = t >> 6;
  const int wm = w >> 1, wn = w & 1;
  f32x4 acc[4][4] = {};
  gemm_tile(AO, Wo, m0, n0, sA, sB, acc, lane, wm, wn, t);
  const int rg = (lane >> 4) * 4, cg = lane & 15;
#pragma unroll
  for (int mi = 0; mi < 4; ++mi)
#pragma unroll
    for (int ni = 0; ni < 4; ++ni) {
      int m = m0 + wm * 64 + mi * 16 + rg;
      int n = n0 + wn * 64 + ni * 16 + cg;
      float bvx = bo[n];
#pragma unroll
      for (int r = 0; r < 4; ++r)
        out[(size_t)(m + r) * 1024 + n] = acc[mi][ni][r] + bvx;
    }
}

// ---------------- flash attention ----------------
// grid (32 bh, 32 q-tiles of 64), 256 threads = 4 waves, wave w owns 16 q-rows
__global__ __launch_bounds__(256) void attn(
    const __half* __restrict__ Qh, const __half* __restrict__ Kh,
    const __half* __restrict__ Vt, const unsigned char* __restrict__ mb,
    const float* __restrict__ tab, __half* __restrict__ AO) {
  const int bh = blockIdx.x;
  const int q0 = blockIdx.y * 64;
  const int b = bh >> 4, h = bh & 15;
  const int t = threadIdx.x, lane = t & 63, w = t >> 6;
  const int lg = lane >> 4, lr = lane & 15;

  __shared__ float blds[2112];                    // bias slice, index k - qloc + 63
  __shared__ __align__(16) __half pbuf[4][16][72];  // per-wave P transpose buffer

  {
    int off = h * 4095 + 1984 - q0;  // tab[h][rel+2047], rel = i - (q0+63)
    for (int i = t; i < 2111; i += 256) blds[i] = tab[off + i];
  }

  const size_t bh2048 = (size_t)bh * 2048;
  const int qrow = q0 + w * 16 + lr;
  const __half* qp = Qh + (bh2048 + qrow) * 64 + lg * 8;
  f16x8 aq0 = *(const f16x8*)qp;
  f16x8 aq1 = *(const f16x8*)(qp + 32);

  const __half* Kb = Kh + bh2048 * 64;
  const __half* Vb = Vt + bh2048 * 64;  // [64][2048]
  const unsigned char* mbb = mb + (size_t)b * L_ * L_;

  f32x4 o[4] = {};
  float mrun[4] = {-1e38f, -1e38f, -1e38f, -1e38f};
  float lrun[4] = {0.f, 0.f, 0.f, 0.f};

  __syncthreads();

  for (int k0 = 0; k0 < L_; k0 += 64) {
    // S = Q K^T (scale pre-folded into Q)
    f32x4 s[4] = {};
#pragma unroll
    for (int ct = 0; ct < 4; ++ct) {
      const __half* kp = Kb + (size_t)(k0 + ct * 16 + lr) * 64 + lg * 8;
      f16x8 b0 = *(const f16x8*)kp;
      f16x8 b1 = *(const f16x8*)(kp + 32);
      s[ct] = __builtin_amdgcn_mfma_f32_16x16x32_f16(aq0, b0, s[ct], 0, 0, 0);
      s[ct] = __builtin_amdgcn_mfma_f32_16x16x32_f16(aq1, b1, s[ct], 0, 0, 0);
    }
    // + bias, then mask
    const int qloc = w * 16 + lg * 4;  // + r
#pragma unroll
    for (int ct = 0; ct < 4; ++ct) {
      int k = k0 + ct * 16 + lr;
      const unsigned char* mp = mbb + (size_t)(q0 + qloc) * L_ + k;
#pragma unroll
      for (int r = 0; r < 4; ++r) {
        float sv = s[ct][r] + blds[k - qloc - r + 63];
        s[ct][r] = mp[(size_t)r * L_] ? sv : -1e9f;
      }
    }
    // online softmax (rows live in 16-lane groups)
#pragma unroll
    for (int r = 0; r < 4; ++r) {
      float vm = fmaxf(fmaxf(s[0][r], s[1][r]), fmaxf(s[2][r], s[3][r]));
#pragma unroll
      for (int d = 1; d < 16; d <<= 1) vm = fmaxf(vm, __shfl_xor(vm, d, 64));
      float mn = fmaxf(mrun[r], vm);
      float sc = __expf(mrun[r] - mn);
      float ps = 0.f;
#pragma unroll
      for (int ct = 0; ct < 4; ++ct) {
        float p = __expf(s[ct][r] - mn);
        s[ct][r] = p;
        ps += p;
      }
#pragma unroll
      for (int d = 1; d < 16; d <<= 1) ps += __shfl_xor(ps, d, 64);
      lrun[r] = lrun[r] * sc + ps;
      mrun[r] = mn;
#pragma unroll
      for (int dt = 0; dt < 4; ++dt) o[dt][r] *= sc;
    }
    // P -> LDS (transpose to A-fragment layout)
#pragma unroll
    for (int ct = 0; ct < 4; ++ct)
#pragma unroll
      for (int r = 0; r < 4; ++r)
        pbuf[w][lg * 4 + r][ct * 16 + lr] = __float2half(s[ct][r]);
    __syncthreads();
    // O += P V
#pragma unroll
    for (int kk = 0; kk < 2; ++kk) {
      f16x8 ap = *(const f16x8*)&pbuf[w][lr][kk * 32 + lg * 8];
#pragma unroll
      for (int dt = 0; dt < 4; ++dt) {
        const __half* vp = Vb + (size_t)(dt * 16 + lr) * 2048 + k0 + kk * 32 + lg * 8;
        f16x8 bv = *(const f16x8*)vp;
        o[dt] = __builtin_amdgcn_mfma_f32_16x16x32_f16(ap, bv, o[dt], 0, 0, 0);
      }
    }
    __syncthreads();
  }
  // epilogue: normalize and store
#pragma unroll
  for (int dt = 0; dt < 4; ++dt) {
    int dd = dt * 16 + lr;
#pragma unroll
    for (int r = 0; r < 4; ++r) {
      int qg = q0 + w * 16 + lg * 4 + r;
      float v = o[dt][r] / lrun[r];
      AO[((size_t)(b * L_ + qg)) * D_ + h * 64 + dd] = __float2half(v);
    }
  }
}

// ---------------- launch ----------------
extern "C" void kernel_launch(void* const* d_in, const int* in_sizes, int n_in,
                              void* d_out, int out_size, void* d_ws, size_t ws_size,
                              hipStream_t stream) {
  const float* x = (const float*)d_in[0];
  const int* mask = (const int*)d_in[1];
  const float* Wq_w = (const float*)d_in[2];
  const float* Wq_b = (const float*)d_in[3];
  const float* Wk_w = (const float*)d_in[4];
  const float* Wk_b = (const float*)d_in[5];
  const float* Wv_w = (const float*)d_in[6];
  const float* Wv_b = (const float*)d_in[7];
  const float* Wo_w = (const float*)d_in[8];
  const float* Wo_b = (const float*)d_in[9];
  const float* rel_emb = (const float*)d_in[10];
  float* out = (float*)d_out;

  char* ws = (char*)d_ws;
  const size_t MB = 1024 * 1024;
  __half* xh = (__half*)(ws);              // 8 MiB, also reused as AO
  __half* wqh = (__half*)(ws + 8 * MB);    // 2 MiB
  __half* wkh = (__half*)(ws + 10 * MB);
  __half* wvh = (__half*)(ws + 12 * MB);
  __half* woh = (__half*)(ws + 14 * MB);
  __half* Qh = (__half*)(ws + 16 * MB);    // 8 MiB [32][2048][64]
  __half* Kh = (__half*)(ws + 24 * MB);    // 8 MiB
  __half* Vt = (__half*)(ws + 32 * MB);    // 8 MiB [32][64][2048]
  unsigned char* mb = (unsigned char*)(ws + 40 * MB);  // 8 MiB
  float* tab = (float*)(ws + 48 * MB);     // 256 KiB
  __half* AO = xh;  // x no longer needed after QKV GEMM

  cvt_f16<<<4096, 256, 0, stream>>>(x, xh, 1048576);
  cvt_f16<<<1024, 256, 0, stream>>>(Wq_w, wqh, 262144);
  cvt_f16<<<1024, 256, 0, stream>>>(Wk_w, wkh, 262144);
  cvt_f16<<<1024, 256, 0, stream>>>(Wv_w, wvh, 262144);
  cvt_f16<<<1024, 256, 0, stream>>>(Wo_w, woh, 262144);
  cvt_mask<<<8192, 256, 0, stream>>>(mask, mb, 2097152);
  bias_table<<<256, 256, 0, stream>>>(rel_emb, tab);

  gemm_qkv<<<dim3(32, 24), 256, 0, stream>>>(xh, wqh, wkh, wvh, Wq_b, Wk_b, Wv_b, Qh, Kh, Vt);
  attn<<<dim3(32, 32), 256, 0, stream>>>(Qh, Kh, Vt, mb, tab, AO);
  gemm_out<<<dim3(32, 8), 256, 0, stream>>>(AO, woh, Wo_b, out);
}

// Round 2
// 240.306 us; speedup vs baseline: 1.4449x; 1.4449x over previous
//
#include <hip/hip_runtime.h>
#include <hip/hip_fp16.h>

#define B_ 2
#define L_ 2048
#define D_ 1024
#define H_ 16

typedef __attribute__((ext_vector_type(8))) _Float16 f16x8;
typedef __attribute__((ext_vector_type(4))) float f32x4;

__device__ __forceinline__ void gload_lds16(const void* g, void* l) {
  __builtin_amdgcn_global_load_lds(
      (const __attribute__((address_space(1))) unsigned int*)g,
      (__attribute__((address_space(3))) unsigned int*)l, 16, 0, 0);
}

// ---------------- converts ----------------
__global__ __launch_bounds__(256) void cvt_f16(const float* __restrict__ s,
                                               __half* __restrict__ d, int n4) {
  int i = blockIdx.x * 256 + threadIdx.x;
  if (i >= n4) return;
  float4 v = ((const float4*)s)[i];
  __half2* o = (__half2*)(d + (size_t)i * 4);
  o[0] = __floats2half2_rn(v.x, v.y);
  o[1] = __floats2half2_rn(v.z, v.w);
}

// pack mask int32 -> bitmask u64, one wave per 64 ints
__global__ __launch_bounds__(256) void pack_mask(const int* __restrict__ m,
                                                 unsigned long long* __restrict__ bits) {
  int wword = blockIdx.x * 4 + (threadIdx.x >> 6);
  int lane = threadIdx.x & 63;
  int v = m[(size_t)wword * 64 + lane];
  unsigned long long bal = __ballot(v != 0);
  if (lane == 0) bits[wword] = bal;
}

// T5 bucket -> bias table [H][4095], index = rel + 2047
__global__ __launch_bounds__(256) void bias_table(const float* __restrict__ rel_emb,
                                                  float* __restrict__ tab) {
  int i = blockIdx.x * 256 + threadIdx.x;
  if (i >= H_ * 4095) return;
  int h = i / 4095, idx = i - h * 4095;
  int rel = idx - 2047;
  int n = rel < 0 ? -rel : rel;
  int bkt;
  if (n < 8) {
    bkt = n;
  } else {
    float t = logf((float)n / 8.0f) / 2.772588722239781f * 8.0f;
    int v = 8 + (int)t;
    bkt = v < 15 ? v : 15;
  }
  if (rel > 0) bkt += 16;
  tab[i] = rel_emb[bkt * H_ + h];
}

// ---------------- GEMM core: C[128x128] = A[M,1024] * W[N,1024]^T ----------------
__device__ __forceinline__ void gemm_tile(const __half* __restrict__ A,
                                          const __half* __restrict__ Bw,
                                          int m0, int n0,
                                          __half* sA, __half* sB,
                                          f32x4 (&acc)[4][4],
                                          int lane, int wm, int wn, int t) {
  for (int k0 = 0; k0 < 1024; k0 += 64) {
    __syncthreads();
#pragma unroll
    for (int it = 0; it < 4; ++it) {
      int c = t + it * 256;
      int row = c >> 3, seg = c & 7;
      gload_lds16(A + ((size_t)(m0 + row) << 10) + k0 + seg * 8, sA + c * 8);
      gload_lds16(Bw + ((size_t)(n0 + row) << 10) + k0 + seg * 8, sB + c * 8);
    }
    __syncthreads();
#pragma unroll
    for (int kk = 0; kk < 2; ++kk) {
      const int off = kk * 32 + (lane >> 4) * 8;
      const int rr = lane & 15;
      f16x8 af[4], bf[4];
#pragma unroll
      for (int i = 0; i < 4; ++i) af[i] = *(const f16x8*)&sA[(wm * 64 + i * 16 + rr) * 64 + off];
#pragma unroll
      for (int i = 0; i < 4; ++i) bf[i] = *(const f16x8*)&sB[(wn * 64 + i * 16 + rr) * 64 + off];
#pragma unroll
      for (int mi = 0; mi < 4; ++mi)
#pragma unroll
        for (int ni = 0; ni < 4; ++ni)
          acc[mi][ni] = __builtin_amdgcn_mfma_f32_16x16x32_f16(af[mi], bf[ni], acc[mi][ni], 0, 0, 0);
    }
  }
}

// fused QKV projection: grid (32, 24); widx = which weight
__global__ __launch_bounds__(256) void gemm_qkv(
    const __half* __restrict__ xh,
    const __half* __restrict__ Wq, const __half* __restrict__ Wk, const __half* __restrict__ Wv,
    const float* __restrict__ bq, const float* __restrict__ bk, const float* __restrict__ bvv,
    __half* __restrict__ Qh, __half* __restrict__ Kh, __half* __restrict__ Vt) {
  __shared__ __align__(16) __half sA[128 * 64];
  __shared__ __align__(16) __half sB[128 * 64];
  const int m0 = blockIdx.x * 128;
  const int ng = blockIdx.y * 128;
  const int widx = ng >> 10;
  const int n0 = ng & 1023;
  const __half* Bw = widx == 0 ? Wq : (widx == 1 ? Wk : Wv);
  const float* bias = widx == 0 ? bq : (widx == 1 ? bk : bvv);
  const int t = threadIdx.x, lane = t & 63, w = t >> 6;
  const int wm = w >> 1, wn = w & 1;
  f32x4 acc[4][4] = {};
  gemm_tile(xh, Bw, m0, n0, sA, sB, acc, lane, wm, wn, t);
  const int rg = (lane >> 4) * 4, cg = lane & 15;
#pragma unroll
  for (int mi = 0; mi < 4; ++mi)
#pragma unroll
    for (int ni = 0; ni < 4; ++ni) {
      int m = m0 + wm * 64 + mi * 16 + rg;
      int n = n0 + wn * 64 + ni * 16 + cg;
      float bvx = bias[n];
      int b = m >> 11, l = m & 2047, hh = n >> 6, dd = n & 63;
      f32x4 a = acc[mi][ni];
      if (widx == 2) {
        size_t base = ((size_t)((b * 16 + hh) * 64 + dd)) * 2048 + l;
        __half2 p0 = __floats2half2_rn(a.x + bvx, a.y + bvx);
        __half2 p1 = __floats2half2_rn(a.z + bvx, a.w + bvx);
        *(__half2*)(Vt + base) = p0;
        *(__half2*)(Vt + base + 2) = p1;
      } else {
        __half* dst = widx == 0 ? Qh : Kh;
        float scf = widx == 0 ? 0.125f : 1.0f;  // fold 1/sqrt(dk) into Q
        size_t base = (((size_t)(b * 16 + hh)) * 2048 + l) * 64 + dd;
#pragma unroll
        for (int r = 0; r < 4; ++r)
          dst[base + (size_t)r * 64] = __float2half((a[r] + bvx) * scf);
      }
    }
}

// output projection: out = AO * Wo^T + bo, fp32 result
__global__ __launch_bounds__(256) void gemm_out(
    const __half* __restrict__ AO, const __half* __restrict__ Wo,
    const float* __restrict__ bo, float* __restrict__ out) {
  __shared__ __align__(16) __half sA[128 * 64];
  __shared__ __align__(16) __half sB[128 * 64];
  const int m0 = blockIdx.x * 128;
  const int n0 = blockIdx.y * 128;
  const int t = threadIdx.x, lane = t & 63, w = t >> 6;
  const int wm = w >> 1, wn = w & 1;
  f32x4 acc[4][4] = {};
  gemm_tile(AO, Wo, m0, n0, sA, sB, acc, lane, wm, wn, t);
  const int rg = (lane >> 4) * 4, cg = lane & 15;
#pragma unroll
  for (int mi = 0; mi < 4; ++mi)
#pragma unroll
    for (int ni = 0; ni < 4; ++ni) {
      int m = m0 + wm * 64 + mi * 16 + rg;
      int n = n0 + wn * 64 + ni * 16 + cg;
      float bvx = bo[n];
#pragma unroll
      for (int r = 0; r < 4; ++r)
        out[(size_t)(m + r) * 1024 + n] = acc[mi][ni][r] + bvx;
    }
}

// ---------------- flash attention ----------------
// grid: 1024 linear blocks, XCD-chunked: each XCD owns 4 heads (K/V L2-resident).
// 4 waves, wave w owns q-rows [q0+16w, q0+16w+16). K/V tiles staged in LDS,
// double-buffered, seg-XOR swizzled (rule 21: inverse-swz source + swz read).
__global__ __launch_bounds__(256) void attn(
    const __half* __restrict__ Qh, const __half* __restrict__ Kh,
    const __half* __restrict__ Vt, const unsigned long long* __restrict__ mb64,
    const float* __restrict__ tab, __half* __restrict__ AO) {
  const int id = blockIdx.x;
  const int ii = id >> 3;
  const int bh = (id & 7) * 4 + (ii >> 5);  // perf-only swizzle (bijective)
  const int q0 = (ii & 31) * 64;
  const int b = bh >> 4, h = bh & 15;
  const int t = threadIdx.x, lane = t & 63, w = t >> 6;
  const int lg = lane >> 4, lr = lane & 15;

  __shared__ float blds[2112];
  __shared__ __align__(16) __half sK[2][64 * 64];
  __shared__ __align__(16) __half sV[2][64 * 64];
  __shared__ __align__(16) __half pbuf[4][16][72];

  {
    int off = h * 4095 + 1984 - q0;  // blds[i] = bias(rel = i - 63 - q0 ... )
    for (int i = t; i < 2111; i += 256) blds[i] = tab[off + i];
  }

  const size_t bh2048 = (size_t)bh * 2048;
  const int qrow = q0 + w * 16 + lr;
  const __half* qp = Qh + (bh2048 + qrow) * 64 + lg * 8;
  f16x8 aq0 = *(const f16x8*)qp;
  f16x8 aq1 = *(const f16x8*)(qp + 32);

  const __half* Kb = Kh + bh2048 * 64;
  const __half* Vb = Vt + bh2048 * 64;  // [64][2048]
  const int qloc = w * 16 + lg * 4;     // + r
  const unsigned long long* mrow = mb64 + ((size_t)(b * 2048 + q0 + qloc)) * 32;

  f32x4 o[4] = {};
  float mrun[4] = {-1e38f, -1e38f, -1e38f, -1e38f};
  float lrun[4] = {0.f, 0.f, 0.f, 0.f};

  __half* k_cur = sK[0]; __half* k_nxt = sK[1];
  __half* v_cur = sV[0]; __half* v_nxt = sV[1];

  // prologue: stage tile 0 (source pre-swizzled so LDS slot (row,seg) holds
  // global segment seg^(row&7); reads below apply the same XOR)
#pragma unroll
  for (int it = 0; it < 2; ++it) {
    int c = t + it * 256;
    int row = c >> 3, seg = c & 7;
    int gs = (seg ^ row) & 7;
    gload_lds16(Kb + ((size_t)row << 6) + gs * 8, k_cur + c * 8);
    gload_lds16(Vb + ((size_t)row << 11) + gs * 8, v_cur + c * 8);
  }
  __syncthreads();  // drains vmcnt(0): tile 0 staged, blds ready

  for (int k0 = 0; k0 < L_; k0 += 64) {
    if (k0 + 64 < L_) {
#pragma unroll
      for (int it = 0; it < 2; ++it) {
        int c = t + it * 256;
        int row = c >> 3, seg = c & 7;
        int gs = (seg ^ row) & 7;
        gload_lds16(Kb + ((size_t)(k0 + 64 + row) << 6) + gs * 8, k_nxt + c * 8);
        gload_lds16(Vb + ((size_t)row << 11) + (k0 + 64) + gs * 8, v_nxt + c * 8);
      }
    }
    // S = Q K^T from LDS (scale pre-folded into Q)
    f32x4 s[4] = {};
#pragma unroll
    for (int ct = 0; ct < 4; ++ct) {
      int row = ct * 16 + lr;
      const char* rbase = (const char*)k_cur + row * 128;
      f16x8 b0 = *(const f16x8*)(rbase + (((lg ^ row) & 7) << 4));
      f16x8 b1 = *(const f16x8*)(rbase + ((((lg + 4) ^ row) & 7) << 4));
      s[ct] = __builtin_amdgcn_mfma_f32_16x16x32_f16(aq0, b0, s[ct], 0, 0, 0);
      s[ct] = __builtin_amdgcn_mfma_f32_16x16x32_f16(aq1, b1, s[ct], 0, 0, 0);
    }
    // bias + bit-mask
    unsigned long long mw[4];
#pragma unroll
    for (int r = 0; r < 4; ++r) mw[r] = mrow[(size_t)r * 32 + (k0 >> 6)];
#pragma unroll
    for (int ct = 0; ct < 4; ++ct) {
      int k = k0 + ct * 16 + lr;
#pragma unroll
      for (int r = 0; r < 4; ++r) {
        float sv_ = s[ct][r] + blds[k - qloc - r + 63];
        s[ct][r] = ((mw[r] >> (ct * 16 + lr)) & 1ull) ? sv_ : -1e9f;
      }
    }
    // online softmax (rows live in 16-lane groups)
#pragma unroll
    for (int r = 0; r < 4; ++r) {
      float vm = fmaxf(fmaxf(s[0][r], s[1][r]), fmaxf(s[2][r], s[3][r]));
#pragma unroll
      for (int d = 1; d < 16; d <<= 1) vm = fmaxf(vm, __shfl_xor(vm, d, 64));
      float mn = fmaxf(mrun[r], vm);
      float sc = __expf(mrun[r] - mn);
      float ps = 0.f;
#pragma unroll
      for (int ct = 0; ct < 4; ++ct) {
        float p = __expf(s[ct][r] - mn);
        s[ct][r] = p;
        ps += p;
      }
#pragma unroll
      for (int d = 1; d < 16; d <<= 1) ps += __shfl_xor(ps, d, 64);
      lrun[r] = lrun[r] * sc + ps;
      mrun[r] = mn;
#pragma unroll
      for (int dt = 0; dt < 4; ++dt) o[dt][r] *= sc;
    }
    // P -> per-wave LDS transpose (no block barrier needed: wave-private)
#pragma unroll
    for (int ct = 0; ct < 4; ++ct)
#pragma unroll
      for (int r = 0; r < 4; ++r)
        pbuf[w][lg * 4 + r][ct * 16 + lr] = __float2half(s[ct][r]);
    // O += P V from LDS
#pragma unroll
    for (int kk = 0; kk < 2; ++kk) {
      f16x8 ap = *(const f16x8*)&pbuf[w][lr][kk * 32 + lg * 8];
#pragma unroll
      for (int dt = 0; dt < 4; ++dt) {
        int row = dt * 16 + lr;
        int seg = kk * 4 + lg;
        const char* rb = (const char*)v_cur + row * 128;
        f16x8 bv = *(const f16x8*)(rb + (((seg ^ row) & 7) << 4));
        o[dt] = __builtin_amdgcn_mfma_f32_16x16x32_f16(ap, bv, o[dt], 0, 0, 0);
      }
    }
    __syncthreads();  // drains vmcnt(0): next tile staged; all waves done with cur
    __half* tk = k_cur; k_cur = k_nxt; k_nxt = tk;
    __half* tv = v_cur; v_cur = v_nxt; v_nxt = tv;
  }
  // epilogue: normalize and store
#pragma unroll
  for (int dt = 0; dt < 4; ++dt) {
    int dd = dt * 16 + lr;
#pragma unroll
    for (int r = 0; r < 4; ++r) {
      int qg = q0 + w * 16 + lg * 4 + r;
      float v = o[dt][r] / lrun[r];
      AO[((size_t)(b * L_ + qg)) * D_ + h * 64 + dd] = __float2half(v);
    }
  }
}

// ---------------- launch ----------------
extern "C" void kernel_launch(void* const* d_in, const int* in_sizes, int n_in,
                              void* d_out, int out_size, void* d_ws, size_t ws_size,
                              hipStream_t stream) {
  const float* x = (const float*)d_in[0];
  const int* mask = (const int*)d_in[1];
  const float* Wq_w = (const float*)d_in[2];
  const float* Wq_b = (const float*)d_in[3];
  const float* Wk_w = (const float*)d_in[4];
  const float* Wk_b = (const float*)d_in[5];
  const float* Wv_w = (const float*)d_in[6];
  const float* Wv_b = (const float*)d_in[7];
  const float* Wo_w = (const float*)d_in[8];
  const float* Wo_b = (const float*)d_in[9];
  const float* rel_emb = (const float*)d_in[10];
  float* out = (float*)d_out;

  char* ws = (char*)d_ws;
  const size_t MB = 1024 * 1024;
  __half* xh = (__half*)(ws);              // 8 MiB, reused as AO
  __half* wqh = (__half*)(ws + 8 * MB);
  __half* wkh = (__half*)(ws + 10 * MB);
  __half* wvh = (__half*)(ws + 12 * MB);
  __half* woh = (__half*)(ws + 14 * MB);
  __half* Qh = (__half*)(ws + 16 * MB);    // [32][2048][64]
  __half* Kh = (__half*)(ws + 24 * MB);
  __half* Vt = (__half*)(ws + 32 * MB);    // [32][64][2048]
  unsigned long long* mb64 = (unsigned long long*)(ws + 40 * MB);  // 1 MiB
  float* tab = (float*)(ws + 48 * MB);     // 256 KiB
  __half* AO = xh;

  cvt_f16<<<4096, 256, 0, stream>>>(x, xh, 1048576);
  cvt_f16<<<1024, 256, 0, stream>>>(Wq_w, wqh, 262144);
  cvt_f16<<<1024, 256, 0, stream>>>(Wk_w, wkh, 262144);
  cvt_f16<<<1024, 256, 0, stream>>>(Wv_w, wvh, 262144);
  cvt_f16<<<1024, 256, 0, stream>>>(Wo_w, woh, 262144);
  pack_mask<<<32768, 256, 0, stream>>>(mask, mb64);
  bias_table<<<256, 256, 0, stream>>>(rel_emb, tab);

  gemm_qkv<<<dim3(32, 24), 256, 0, stream>>>(xh, wqh, wkh, wvh, Wq_b, Wk_b, Wv_b, Qh, Kh, Vt);
  attn<<<1024, 256, 0, stream>>>(Qh, Kh, Vt, mb64, tab, AO);
  gemm_out<<<dim3(32, 8), 256, 0, stream>>>(AO, woh, Wo_b, out);
}